// Round 8
// baseline (761.966 us; speedup 1.0000x reference)
//
#include <hip/hip_runtime.h>
#include <math.h>

#define BSHIFT 3
#define BROWS 8   // nodes per bucket (requires n < 65536 for 16-bit src packing)

// ---------------- small utils ----------------
__global__ void zero32(int* __restrict__ p, int n) {
    int i = blockIdx.x * blockDim.x + threadIdx.x;
    if (i < n) p[i] = 0;
}

// ---------------- degree / dinv ----------------
__global__ void hist_dst(const int* __restrict__ dst, int* __restrict__ cnt, int E) {
    int e = blockIdx.x * blockDim.x + threadIdx.x;
    if (e < E) atomicAdd(&cnt[dst[e]], 1);
}

__global__ void dinv_from_cnt(const int* __restrict__ cnt, float* __restrict__ dinv, int n) {
    int v = blockIdx.x * blockDim.x + threadIdx.x;
    if (v < n) dinv[v] = rsqrtf((float)(cnt[v] + 1));  // +1 self-loop
}

// bucket sizes from node degrees (no atomics)
__global__ void bucket_cnt(const int* __restrict__ cnt, int* __restrict__ bcnt, int n, int nb) {
    int b = blockIdx.x * blockDim.x + threadIdx.x;
    if (b >= nb) return;
    int v0 = b << BSHIFT;
    int s = 0;
#pragma unroll
    for (int r = 0; r < BROWS; ++r) {
        int v = v0 + r;
        if (v < n) s += cnt[v];
    }
    bcnt[b] = s;
}

// ---- hierarchical scan: 256-elem chunks ----
__global__ __launch_bounds__(256) void scan1(const int* __restrict__ cnt,
                                             int* __restrict__ excl,
                                             int* __restrict__ sums, int n) {
    int i = blockIdx.x * 256 + threadIdx.x;
    int v = (i < n) ? cnt[i] : 0;
    int lane = threadIdx.x & 63;
    int w = threadIdx.x >> 6;
    int s = v;
#pragma unroll
    for (int off = 1; off < 64; off <<= 1) {
        int t = __shfl_up(s, off, 64);
        if (lane >= off) s += t;
    }
    __shared__ int wsum[4];
    if (lane == 63) wsum[w] = s;
    __syncthreads();
    int woff = 0;
#pragma unroll
    for (int k = 0; k < 3; ++k) if (k < w) woff += wsum[k];
    int incl = s + woff;
    if (i < n) excl[i] = incl - v;
    if (threadIdx.x == 255) sums[blockIdx.x] = incl;
}

__global__ __launch_bounds__(256) void scan2(int* __restrict__ sums, int nb) {
    int t = threadIdx.x;
    int v = (t < nb) ? sums[t] : 0;
    int lane = t & 63;
    int w = t >> 6;
    int s = v;
#pragma unroll
    for (int off = 1; off < 64; off <<= 1) {
        int u = __shfl_up(s, off, 64);
        if (lane >= off) s += u;
    }
    __shared__ int wsum[4];
    if (lane == 63) wsum[w] = s;
    __syncthreads();
    int woff = 0;
#pragma unroll
    for (int k = 0; k < 3; ++k) if (k < w) woff += wsum[k];
    int incl = s + woff;
    if (t < nb) sums[t] = incl - v;  // exclusive
}

__global__ __launch_bounds__(256) void scan3b(const int* __restrict__ excl,
                                              const int* __restrict__ sums,
                                              int* __restrict__ boff,
                                              int* __restrict__ cursor, int nb, int E) {
    int i = blockIdx.x * 256 + threadIdx.x;
    if (i < nb) {
        int r = excl[i] + sums[i >> 8];
        boff[i] = r;
        cursor[i] = r;
    }
    if (i == nb) boff[nb] = E;
}

// scatter edges into bucket regions (dense ~1KB regions -> L2-friendly writes)
// payload: .x = src(16b) | local_dst(<<16), .y = edge weight
__global__ void fill_bucket(const int* __restrict__ src, const int* __restrict__ dst,
                            const float* __restrict__ dinv, int* __restrict__ cursor,
                            float2* __restrict__ ebuf, int E) {
    int e = blockIdx.x * blockDim.x + threadIdx.x;
    if (e >= E) return;
    int s = src[e], d = dst[e];
    int p = atomicAdd(&cursor[d >> BSHIFT], 1);
    ebuf[p] = make_float2(__int_as_float(s | ((d & (BROWS - 1)) << 16)),
                          dinv[s] * dinv[d]);
}

// ---------------- GEMM: Y[n,64] = X[n,K] @ W[K,64] ----------------
// Wave owns a row; lane owns output column. W column in VGPRs; row X
// broadcast via v_readlane (SALU) -> inner loop pure FMA, no LDS.
template <int K>
__global__ __launch_bounds__(256) void gemm_bcast(const float* __restrict__ X,
                                                  const float* __restrict__ W,
                                                  float* __restrict__ Y, int n) {
    const int lane = threadIdx.x & 63;
    const long wid = (((long)blockIdx.x * blockDim.x) + threadIdx.x) >> 6;
    const long nw  = ((long)gridDim.x * blockDim.x) >> 6;

    float wr[K];
#pragma unroll
    for (int k = 0; k < K; ++k) wr[k] = W[k * 64 + lane];  // coalesced per k

    long r = wid;
    if (r >= n) return;
    float xa = X[r * K + lane];
    float xb = 0.f;
    if constexpr (K > 64) xb = X[r * K + 64 + lane];

    while (true) {
        long rn = r + nw;
        bool more = rn < n;
        long rc = more ? rn : r;
        float xan = X[rc * K + lane];
        float xbn = 0.f;
        if constexpr (K > 64) xbn = X[rc * K + 64 + lane];

        float a0 = 0.f, a1 = 0.f, a2 = 0.f, a3 = 0.f;
#pragma unroll
        for (int k = 0; k < 64; k += 4) {
            a0 = fmaf(__int_as_float(__builtin_amdgcn_readlane(__float_as_int(xa), k + 0)), wr[k + 0], a0);
            a1 = fmaf(__int_as_float(__builtin_amdgcn_readlane(__float_as_int(xa), k + 1)), wr[k + 1], a1);
            a2 = fmaf(__int_as_float(__builtin_amdgcn_readlane(__float_as_int(xa), k + 2)), wr[k + 2], a2);
            a3 = fmaf(__int_as_float(__builtin_amdgcn_readlane(__float_as_int(xa), k + 3)), wr[k + 3], a3);
        }
        if constexpr (K > 64) {
#pragma unroll
            for (int k = 0; k < 64; k += 4) {
                a0 = fmaf(__int_as_float(__builtin_amdgcn_readlane(__float_as_int(xb), k + 0)), wr[64 + k + 0], a0);
                a1 = fmaf(__int_as_float(__builtin_amdgcn_readlane(__float_as_int(xb), k + 1)), wr[64 + k + 1], a1);
                a2 = fmaf(__int_as_float(__builtin_amdgcn_readlane(__float_as_int(xb), k + 2)), wr[64 + k + 2], a2);
                a3 = fmaf(__int_as_float(__builtin_amdgcn_readlane(__float_as_int(xb), k + 3)), wr[64 + k + 3], a3);
            }
        }
        Y[r * 64 + lane] = (a0 + a1) + (a2 + a3);
        if (!more) break;
        r = rn;
        xa = xan;
        xb = xbn;
    }
}

// ---------------- bucket aggregation: wave per bucket, LDS accum ----------------
// acc[BROWS][64] in LDS; edges streamed sequentially; gathers unrolled 4x;
// fire-and-forget LDS atomicAdd (no dependent chain). Self-loop+bias+relu fused.
__global__ __launch_bounds__(256) void bucket_agg(const float* __restrict__ H,
                                                  const float2* __restrict__ ebuf,
                                                  const int* __restrict__ boff,
                                                  const float* __restrict__ dinv,
                                                  const float* __restrict__ bias,
                                                  float* __restrict__ out,
                                                  int n, int nbuckets) {
    const int j  = threadIdx.x & 63;
    const int wv = threadIdx.x >> 6;
    const int b  = blockIdx.x * 4 + wv;
    __shared__ float accs[4][BROWS * 64];
    if (b >= nbuckets) return;
    float* A = accs[wv];
    const int v0 = b << BSHIFT;
    const float bj = bias[j];
#pragma unroll
    for (int r = 0; r < BROWS; ++r) {
        long v = v0 + r;
        float init = 0.f;
        if (v < n) {
            float di = dinv[v];
            init = H[v * 64 + j] * di * di + bj;
        }
        A[r * 64 + j] = init;
    }
    int p = boff[b], p1 = boff[b + 1];
    for (; p + 4 <= p1; p += 4) {
        float2 e0 = ebuf[p + 0];
        float2 e1 = ebuf[p + 1];
        float2 e2 = ebuf[p + 2];
        float2 e3 = ebuf[p + 3];
        int k0 = __float_as_int(e0.x);
        int k1 = __float_as_int(e1.x);
        int k2 = __float_as_int(e2.x);
        int k3 = __float_as_int(e3.x);
        float h0 = H[(long)(k0 & 0xFFFF) * 64 + j];
        float h1 = H[(long)(k1 & 0xFFFF) * 64 + j];
        float h2 = H[(long)(k2 & 0xFFFF) * 64 + j];
        float h3 = H[(long)(k3 & 0xFFFF) * 64 + j];
        atomicAdd(&A[(k0 >> 16) * 64 + j], h0 * e0.y);
        atomicAdd(&A[(k1 >> 16) * 64 + j], h1 * e1.y);
        atomicAdd(&A[(k2 >> 16) * 64 + j], h2 * e2.y);
        atomicAdd(&A[(k3 >> 16) * 64 + j], h3 * e3.y);
    }
    for (; p < p1; ++p) {
        float2 e = ebuf[p];
        int k = __float_as_int(e.x);
        atomicAdd(&A[(k >> 16) * 64 + j], H[(long)(k & 0xFFFF) * 64 + j] * e.y);
    }
    // compiler inserts lgkmcnt wait: reads below alias the LDS atomics above
#pragma unroll
    for (int r = 0; r < BROWS; ++r) {
        long v = v0 + r;
        if (v < n) out[v * 64 + j] = fmaxf(A[r * 64 + j], 0.f);
    }
}

// ---------------- pooling: LDS-privatized partials, no global atomics ----------------
__global__ __launch_bounds__(256) void pool_part(const float* __restrict__ H,
                                                 const float* __restrict__ Wl,
                                                 const int* __restrict__ batch,
                                                 float* __restrict__ part,
                                                 float* __restrict__ partc, int n) {
    __shared__ float lp[256];
    __shared__ float lc[256];
    lp[threadIdx.x] = 0.f;
    lc[threadIdx.x] = 0.f;
    __syncthreads();
    const int j  = threadIdx.x & 63;
    const int wv = threadIdx.x >> 6;
    for (long v = (long)blockIdx.x * 4 + wv; v < n; v += (long)gridDim.x * 4) {
        float valx = H[v * 64 + j] * Wl[j];
#pragma unroll
        for (int off = 32; off > 0; off >>= 1) valx += __shfl_down(valx, off, 64);
        if (j == 0) {
            int g = batch[v];
            atomicAdd(&lp[g], valx);
            atomicAdd(&lc[g], 1.0f);
        }
    }
    __syncthreads();
    long o = (long)blockIdx.x * 256 + threadIdx.x;
    part[o]  = lp[threadIdx.x];
    partc[o] = lc[threadIdx.x];
}

__global__ __launch_bounds__(256) void pool_final(const float* __restrict__ part,
                                                  const float* __restrict__ partc,
                                                  const float* __restrict__ bl,
                                                  float* __restrict__ out, int nblk) {
    int g = blockIdx.x;
    int t = threadIdx.x;
    float s = 0.f, c = 0.f;
    for (int b = t; b < nblk; b += 256) {
        s += part[(long)b * 256 + g];
        c += partc[(long)b * 256 + g];
    }
    __shared__ float sp[256];
    __shared__ float sc[256];
    sp[t] = s;
    sc[t] = c;
    __syncthreads();
    for (int off = 128; off > 0; off >>= 1) {
        if (t < off) { sp[t] += sp[t + off]; sc[t] += sc[t + off]; }
        __syncthreads();
    }
    if (t == 0) out[g] = sp[0] / fmaxf(sc[0], 1.0f) + bl[0];
}

extern "C" void kernel_launch(void* const* d_in, const int* in_sizes, int n_in,
                              void* d_out, int out_size, void* d_ws, size_t ws_size,
                              hipStream_t stream) {
    const float* x  = (const float*)d_in[0];
    const float* W1 = (const float*)d_in[1];
    const float* b1 = (const float*)d_in[2];
    const float* W2 = (const float*)d_in[3];
    const float* b2 = (const float*)d_in[4];
    const float* Wl = (const float*)d_in[5];
    const float* bl = (const float*)d_in[6];
    const int* edge_index = (const int*)d_in[7];
    const int* batch      = (const int*)d_in[8];

    const int n = in_sizes[0] / 128;   // 50000
    const int E = in_sizes[7] / 2;     // 800000
    const int G = out_size;            // 256
    const int* src = edge_index;
    const int* dst = edge_index + E;
    const int nb = (n + BROWS - 1) >> BSHIFT;  // 6250 buckets

    char* ws = (char*)d_ws;
    size_t off = 0;
    auto alloc = [&](size_t bytes) { void* p = ws + off; off = (off + bytes + 255) & ~(size_t)255; return p; };
    int*    cntv   = (int*)   alloc((size_t)n * 4);
    float*  dinv   = (float*) alloc((size_t)n * 4);
    int*    bcnt   = (int*)   alloc((size_t)nb * 4);
    int*    boff   = (int*)   alloc((size_t)(nb + 1) * 4);
    int*    cursor = (int*)   alloc((size_t)nb * 4);
    int*    excl   = (int*)   alloc((size_t)nb * 4);
    int*    sums   = (int*)   alloc((size_t)256 * 4);
    float2* ebuf   = (float2*)alloc((size_t)E * 8);
    float*  bufA   = (float*) alloc((size_t)n * 64 * 4);
    float*  bufB   = (float*) alloc((size_t)n * 64 * 4);
    const int PBLK = 1024;
    float*  part   = (float*) alloc((size_t)PBLK * 256 * 4);
    float*  partc  = (float*) alloc((size_t)PBLK * 256 * 4);

    const int T = 256;
    const int nchunks = (nb + 255) / 256;  // 25 <= 256
    // ---- degrees + bucket layout (shared by both layers) ----
    zero32<<<(n + T - 1) / T, T, 0, stream>>>(cntv, n);
    hist_dst<<<(E + T - 1) / T, T, 0, stream>>>(dst, cntv, E);
    dinv_from_cnt<<<(n + T - 1) / T, T, 0, stream>>>(cntv, dinv, n);
    bucket_cnt<<<(nb + T - 1) / T, T, 0, stream>>>(cntv, bcnt, n, nb);
    scan1<<<nchunks, T, 0, stream>>>(bcnt, excl, sums, nb);
    scan2<<<1, T, 0, stream>>>(sums, nchunks);
    scan3b<<<(nb + 1 + T - 1) / T, T, 0, stream>>>(excl, sums, boff, cursor, nb, E);
    fill_bucket<<<(E + T - 1) / T, T, 0, stream>>>(src, dst, dinv, cursor, ebuf, E);

    const int ggrid = 768;
    const int agrid = (nb + 3) / 4;
    // ---- layer 1 ----
    gemm_bcast<128><<<ggrid, T, 0, stream>>>(x, W1, bufA, n);
    bucket_agg<<<agrid, T, 0, stream>>>(bufA, ebuf, boff, dinv, b1, bufB, n, nb);

    // ---- layer 2 ----
    gemm_bcast<64><<<ggrid, T, 0, stream>>>(bufB, W2, bufA, n);
    bucket_agg<<<agrid, T, 0, stream>>>(bufA, ebuf, boff, dinv, b2, bufB, n, nb);

    // ---- pooling + head ----
    pool_part<<<PBLK, T, 0, stream>>>(bufB, Wl, batch, part, partc, n);
    pool_final<<<G, T, 0, stream>>>(part, partc, bl, (float*)d_out, PBLK);
}

// Round 9
// 223.708 us; speedup vs baseline: 3.4061x; 3.4061x over previous
//
#include <hip/hip_runtime.h>
#include <math.h>

// ---------------- small utils ----------------
__global__ void zero32(int* __restrict__ p, int n) {
    int i = blockIdx.x * blockDim.x + threadIdx.x;
    if (i < n) p[i] = 0;
}

// ---------------- degree / dinv ----------------
__global__ void hist_dst(const int* __restrict__ dst, int* __restrict__ cnt, int E) {
    int e = blockIdx.x * blockDim.x + threadIdx.x;
    if (e < E) atomicAdd(&cnt[dst[e]], 1);
}

__global__ void dinv_from_cnt(const int* __restrict__ cnt, float* __restrict__ dinv, int n) {
    int v = blockIdx.x * blockDim.x + threadIdx.x;
    if (v < n) dinv[v] = rsqrtf((float)(cnt[v] + 1));  // +1 self-loop
}

// ---- hierarchical scan: 256-elem chunks ----
__global__ __launch_bounds__(256) void scan1(const int* __restrict__ cnt,
                                             int* __restrict__ excl,
                                             int* __restrict__ sums, int n) {
    int i = blockIdx.x * 256 + threadIdx.x;
    int v = (i < n) ? cnt[i] : 0;
    int lane = threadIdx.x & 63;
    int w = threadIdx.x >> 6;
    int s = v;
#pragma unroll
    for (int off = 1; off < 64; off <<= 1) {
        int t = __shfl_up(s, off, 64);
        if (lane >= off) s += t;
    }
    __shared__ int wsum[4];
    if (lane == 63) wsum[w] = s;
    __syncthreads();
    int woff = 0;
#pragma unroll
    for (int k = 0; k < 3; ++k) if (k < w) woff += wsum[k];
    int incl = s + woff;
    if (i < n) excl[i] = incl - v;
    if (threadIdx.x == 255) sums[blockIdx.x] = incl;
}

__global__ __launch_bounds__(256) void scan2(int* __restrict__ sums, int nb) {
    int t = threadIdx.x;
    int v = (t < nb) ? sums[t] : 0;
    int lane = t & 63;
    int w = t >> 6;
    int s = v;
#pragma unroll
    for (int off = 1; off < 64; off <<= 1) {
        int u = __shfl_up(s, off, 64);
        if (lane >= off) s += u;
    }
    __shared__ int wsum[4];
    if (lane == 63) wsum[w] = s;
    __syncthreads();
    int woff = 0;
#pragma unroll
    for (int k = 0; k < 3; ++k) if (k < w) woff += wsum[k];
    int incl = s + woff;
    if (t < nb) sums[t] = incl - v;  // exclusive
}

__global__ __launch_bounds__(256) void scan3(const int* __restrict__ excl,
                                             const int* __restrict__ sums,
                                             int* __restrict__ rowptr,
                                             int* __restrict__ cursor, int n, int E) {
    int i = blockIdx.x * 256 + threadIdx.x;
    if (i < n) {
        int r = excl[i] + sums[i >> 8];
        rowptr[i] = r;
        cursor[i] = r;
    }
    if (i == n) rowptr[n] = E;
}

// XCD-partitioned CSR fill: blocks with (blockIdx&7)==g handle only dst in
// slice g of the node range -> each XCD's L2 owns a contiguous slice of cv,
// 64B lines fill completely before writeback (kills 8x cross-XCD write amp).
// Pure perf heuristic: correctness independent of block->XCD mapping.
__global__ void fill_csr_part(const int* __restrict__ src, const int* __restrict__ dst,
                              const float* __restrict__ dinv, int* __restrict__ cursor,
                              float2* __restrict__ cv, int E, int n) {
    const int g    = blockIdx.x & 7;
    const int nblk = gridDim.x >> 3;
    const int bid  = blockIdx.x >> 3;
    const int lo = (int)(((long)g * n) >> 3);
    const int hi = (int)(((long)(g + 1) * n) >> 3);
    for (long e = (long)bid * blockDim.x + threadIdx.x; e < E;
         e += (long)nblk * blockDim.x) {
        int d = dst[e];
        if (d < lo || d >= hi) continue;
        int s = src[e];
        int p = atomicAdd(&cursor[d], 1);
        cv[p] = make_float2(__int_as_float(s), dinv[s] * dinv[d]);
    }
}

// ---------------- GEMM: Y[n,64] = X[n,K] @ W[K,64] ----------------
// Wave owns a row; lane owns output column. W column in VGPRs; row X
// broadcast via v_readlane (SALU) -> inner loop pure FMA, no LDS.
template <int K>
__global__ __launch_bounds__(256) void gemm_bcast(const float* __restrict__ X,
                                                  const float* __restrict__ W,
                                                  float* __restrict__ Y, int n) {
    const int lane = threadIdx.x & 63;
    const long wid = (((long)blockIdx.x * blockDim.x) + threadIdx.x) >> 6;
    const long nw  = ((long)gridDim.x * blockDim.x) >> 6;

    float wr[K];
#pragma unroll
    for (int k = 0; k < K; ++k) wr[k] = W[k * 64 + lane];  // coalesced per k

    long r = wid;
    if (r >= n) return;
    float xa = X[r * K + lane];
    float xb = 0.f;
    if constexpr (K > 64) xb = X[r * K + 64 + lane];

    while (true) {
        long rn = r + nw;
        bool more = rn < n;
        long rc = more ? rn : r;
        float xan = X[rc * K + lane];
        float xbn = 0.f;
        if constexpr (K > 64) xbn = X[rc * K + 64 + lane];

        float a0 = 0.f, a1 = 0.f, a2 = 0.f, a3 = 0.f;
#pragma unroll
        for (int k = 0; k < 64; k += 4) {
            a0 = fmaf(__int_as_float(__builtin_amdgcn_readlane(__float_as_int(xa), k + 0)), wr[k + 0], a0);
            a1 = fmaf(__int_as_float(__builtin_amdgcn_readlane(__float_as_int(xa), k + 1)), wr[k + 1], a1);
            a2 = fmaf(__int_as_float(__builtin_amdgcn_readlane(__float_as_int(xa), k + 2)), wr[k + 2], a2);
            a3 = fmaf(__int_as_float(__builtin_amdgcn_readlane(__float_as_int(xa), k + 3)), wr[k + 3], a3);
        }
        if constexpr (K > 64) {
#pragma unroll
            for (int k = 0; k < 64; k += 4) {
                a0 = fmaf(__int_as_float(__builtin_amdgcn_readlane(__float_as_int(xb), k + 0)), wr[64 + k + 0], a0);
                a1 = fmaf(__int_as_float(__builtin_amdgcn_readlane(__float_as_int(xb), k + 1)), wr[64 + k + 1], a1);
                a2 = fmaf(__int_as_float(__builtin_amdgcn_readlane(__float_as_int(xb), k + 2)), wr[64 + k + 2], a2);
                a3 = fmaf(__int_as_float(__builtin_amdgcn_readlane(__float_as_int(xb), k + 3)), wr[64 + k + 3], a3);
            }
        }
        Y[r * 64 + lane] = (a0 + a1) + (a2 + a3);
        if (!more) break;
        r = rn;
        xa = xan;
        xb = xbn;
    }
}

// ---------------- CSR aggregation: one wave per node, unroll-4 MLP ----------------
__global__ __launch_bounds__(256) void agg_relu(const float* __restrict__ H,
                                                const int* __restrict__ rowptr,
                                                const float2* __restrict__ cv,
                                                const float* __restrict__ dinv,
                                                const float* __restrict__ bias,
                                                float* __restrict__ out, int n) {
    long idx = (long)blockIdx.x * blockDim.x + threadIdx.x;
    long v = idx >> 6;
    if (v >= n) return;
    int j = threadIdx.x & 63;
    float di = dinv[v];
    float acc0 = H[v * 64 + j] * di * di + bias[j];
    float acc1 = 0.f, acc2 = 0.f, acc3 = 0.f;
    int p0 = rowptr[v], p1 = rowptr[v + 1];
    int p = p0;
    for (; p + 4 <= p1; p += 4) {
        float2 m0 = cv[p + 0];
        float2 m1 = cv[p + 1];
        float2 m2 = cv[p + 2];
        float2 m3 = cv[p + 3];
        float h0 = H[(long)__float_as_int(m0.x) * 64 + j];
        float h1 = H[(long)__float_as_int(m1.x) * 64 + j];
        float h2 = H[(long)__float_as_int(m2.x) * 64 + j];
        float h3 = H[(long)__float_as_int(m3.x) * 64 + j];
        acc0 += h0 * m0.y;
        acc1 += h1 * m1.y;
        acc2 += h2 * m2.y;
        acc3 += h3 * m3.y;
    }
    for (; p < p1; ++p) {
        float2 m = cv[p];
        acc0 += H[(long)__float_as_int(m.x) * 64 + j] * m.y;
    }
    out[idx] = fmaxf((acc0 + acc1) + (acc2 + acc3), 0.f);
}

// ---------------- pooling: LDS-privatized partials, no global atomics ----------------
__global__ __launch_bounds__(256) void pool_part(const float* __restrict__ H,
                                                 const float* __restrict__ Wl,
                                                 const int* __restrict__ batch,
                                                 float* __restrict__ part,
                                                 float* __restrict__ partc, int n) {
    __shared__ float lp[256];
    __shared__ float lc[256];
    lp[threadIdx.x] = 0.f;
    lc[threadIdx.x] = 0.f;
    __syncthreads();
    const int j  = threadIdx.x & 63;
    const int wv = threadIdx.x >> 6;
    for (long v = (long)blockIdx.x * 4 + wv; v < n; v += (long)gridDim.x * 4) {
        float valx = H[v * 64 + j] * Wl[j];
#pragma unroll
        for (int off = 32; off > 0; off >>= 1) valx += __shfl_down(valx, off, 64);
        if (j == 0) {
            int g = batch[v];
            atomicAdd(&lp[g], valx);
            atomicAdd(&lc[g], 1.0f);
        }
    }
    __syncthreads();
    long o = (long)blockIdx.x * 256 + threadIdx.x;
    part[o]  = lp[threadIdx.x];
    partc[o] = lc[threadIdx.x];
}

__global__ __launch_bounds__(256) void pool_final(const float* __restrict__ part,
                                                  const float* __restrict__ partc,
                                                  const float* __restrict__ bl,
                                                  float* __restrict__ out, int nblk) {
    int g = blockIdx.x;
    int t = threadIdx.x;
    float s = 0.f, c = 0.f;
    for (int b = t; b < nblk; b += 256) {
        s += part[(long)b * 256 + g];
        c += partc[(long)b * 256 + g];
    }
    __shared__ float sp[256];
    __shared__ float sc[256];
    sp[t] = s;
    sc[t] = c;
    __syncthreads();
    for (int off = 128; off > 0; off >>= 1) {
        if (t < off) { sp[t] += sp[t + off]; sc[t] += sc[t + off]; }
        __syncthreads();
    }
    if (t == 0) out[g] = sp[0] / fmaxf(sc[0], 1.0f) + bl[0];
}

extern "C" void kernel_launch(void* const* d_in, const int* in_sizes, int n_in,
                              void* d_out, int out_size, void* d_ws, size_t ws_size,
                              hipStream_t stream) {
    const float* x  = (const float*)d_in[0];
    const float* W1 = (const float*)d_in[1];
    const float* b1 = (const float*)d_in[2];
    const float* W2 = (const float*)d_in[3];
    const float* b2 = (const float*)d_in[4];
    const float* Wl = (const float*)d_in[5];
    const float* bl = (const float*)d_in[6];
    const int* edge_index = (const int*)d_in[7];
    const int* batch      = (const int*)d_in[8];

    const int n = in_sizes[0] / 128;   // 50000
    const int E = in_sizes[7] / 2;     // 800000
    const int G = out_size;            // 256
    const int* src = edge_index;
    const int* dst = edge_index + E;

    char* ws = (char*)d_ws;
    size_t off = 0;
    auto alloc = [&](size_t bytes) { void* p = ws + off; off = (off + bytes + 255) & ~(size_t)255; return p; };
    int*    cntv   = (int*)   alloc((size_t)n * 4);
    float*  dinv   = (float*) alloc((size_t)n * 4);
    int*    rowptr = (int*)   alloc((size_t)(n + 1) * 4);
    int*    cursor = (int*)   alloc((size_t)n * 4);
    int*    excl   = (int*)   alloc((size_t)n * 4);
    int*    sums   = (int*)   alloc((size_t)256 * 4);
    float2* cv     = (float2*)alloc((size_t)E * 8);
    float*  bufA   = (float*) alloc((size_t)n * 64 * 4);
    float*  bufB   = (float*) alloc((size_t)n * 64 * 4);
    const int PBLK = 1024;
    float*  part   = (float*) alloc((size_t)PBLK * 256 * 4);
    float*  partc  = (float*) alloc((size_t)PBLK * 256 * 4);

    const int T = 256;
    const int nchunks = (n + 255) / 256;  // 196 <= 256
    // ---- CSR build (shared by both layers) ----
    zero32<<<(n + T - 1) / T, T, 0, stream>>>(cntv, n);
    hist_dst<<<(E + T - 1) / T, T, 0, stream>>>(dst, cntv, E);
    dinv_from_cnt<<<(n + T - 1) / T, T, 0, stream>>>(cntv, dinv, n);
    scan1<<<nchunks, T, 0, stream>>>(cntv, excl, sums, n);
    scan2<<<1, T, 0, stream>>>(sums, nchunks);
    scan3<<<(n + 1 + T - 1) / T, T, 0, stream>>>(excl, sums, rowptr, cursor, n, E);
    fill_csr_part<<<1024, T, 0, stream>>>(src, dst, dinv, cursor, cv, E, n);

    const int ggrid = 768;
    // ---- layer 1 ----
    gemm_bcast<128><<<ggrid, T, 0, stream>>>(x, W1, bufA, n);
    agg_relu<<<(int)(((long)n * 64 + T - 1) / T), T, 0, stream>>>(bufA, rowptr, cv, dinv, b1, bufB, n);

    // ---- layer 2 ----
    gemm_bcast<64><<<ggrid, T, 0, stream>>>(bufB, W2, bufA, n);
    agg_relu<<<(int)(((long)n * 64 + T - 1) / T), T, 0, stream>>>(bufA, rowptr, cv, dinv, b2, bufB, n);

    // ---- pooling + head ----
    pool_part<<<PBLK, T, 0, stream>>>(bufB, Wl, batch, part, partc, n);
    pool_final<<<G, T, 0, stream>>>(part, partc, bl, (float*)d_out, PBLK);
}